// Round 7
// baseline (128.568 us; speedup 1.0000x reference)
//
#include <hip/hip_runtime.h>
#include <hip/hip_fp16.h>
#include <math.h>

#define B_ 1024
#define F_ 39
#define K_ 16
#define P_ 741
#define T_ 9139
#define NC_ 9880          // P_ + T_
#define EPS_ 1e-3f
#define YSTR 16           // Y row stride in f16 (32 B, no pad; Y reads are reg-cached)
#define ESTR 40           // emb row stride in f16 (80 B: b128 slot=(5c)%8, 5 coprime 8)
#define TBASE 744         // triple column base in padded levels layout (16B-aligned *2B)
#define LS2 9920          // levels row stride in f16 elems (19840 B); also padded col count
#define NG 1240           // LS2/8 uint4 groups per row
#define NSPLIT 32         // stats partial splits (32 rows each)

typedef _Float16 half2v __attribute__((ext_vector_type(2)));

__device__ __forceinline__ float hdot2(unsigned a, unsigned b, float acc) {
    half2v ha = __builtin_bit_cast(half2v, a);
    half2v hb = __builtin_bit_cast(half2v, b);
#if __has_builtin(__builtin_amdgcn_fdot2)
    return __builtin_amdgcn_fdot2(ha, hb, acc, false);
#else
    return acc + (float)ha.x * (float)hb.x + (float)ha.y * (float)hb.y;
#endif
}
__device__ __forceinline__ float f16f(unsigned short h) {
    return __half2float(__builtin_bit_cast(__half, h));
}
__device__ __forceinline__ unsigned short hbits(float x) {
    return __builtin_bit_cast(unsigned short, __float2half(x));
}

// ---------- kernel 0: zero Cacc + pack column descriptors ---------------------------
// pairs  (c < P_):          pidx[c]       = (cols*ESTR) | (rows*ESTR)<<11
// triples(t = c - P_):      pidx[TBASE+t] = (pair_idx*YSTR) | (i3*ESTR)<<15
__global__ __launch_bounds__(256) void prep_k(const int* __restrict__ rows,
                                              const int* __restrict__ cols,
                                              const int* __restrict__ i1,
                                              const int* __restrict__ i2,
                                              const int* __restrict__ i3,
                                              unsigned* __restrict__ pidx,
                                              float* __restrict__ Cacc) {
    int c = blockIdx.x * 256 + threadIdx.x;
    if (c >= NC_) return;
    if (c == 0) Cacc[0] = 0.f;
    if (c < P_) {
        pidx[c] = (unsigned)(cols[c] * ESTR) | ((unsigned)(rows[c] * ESTR) << 11);
    } else {
        int t = c - P_;
        int a = i1[t], b = i2[t], cc = i3[t];
        int p = a * (2 * F_ - 1 - a) / 2 + (b - a - 1);   // lex pair index of (a,b)
        pidx[TBASE + t] = (unsigned)(p * YSTR) | ((unsigned)(cc * ESTR) << 15);
    }
}

// ---------- kernel 1: fused gather + pair products + all level values (f16) ---------
// One batch row per block; 1024 blocks x 512 threads; ~27 KB LDS.
// Each thread owns 18 CONSECUTIVE triples -> Y row register-cached across the run.
__global__ __launch_bounds__(512) void levels_k(const int* __restrict__ feats,
                                                const float* __restrict__ v,
                                                const unsigned* __restrict__ pidx,
                                                unsigned short* __restrict__ levels) {
    int b = blockIdx.x;
    int tid = threadIdx.x;
    __shared__ int tok[F_];
    __shared__ __attribute__((aligned(16))) unsigned short emb2[F_ * ESTR];   // 3120 B
    __shared__ __attribute__((aligned(16))) unsigned short region[P_ * YSTR]; // 23712 B
    unsigned short* Y2 = region;              // phase P0/P1
    unsigned* bufw = (unsigned*)region;       // overlay: triple results after barrier

    unsigned short* lrow = levels + (size_t)b * LS2;

    // prefetch descriptors (loads fly during staging/P0)
    unsigned pk_p0 = (tid < P_) ? pidx[tid] : 0u;
    unsigned pk_p1 = (tid + 512 < P_) ? pidx[tid + 512] : 0u;
    int t0 = 18 * tid;
    unsigned pkt[18];
    {
        const uint2* tp = (const uint2*)(pidx + TBASE + t0);   // 8B-aligned
#pragma unroll
        for (int j = 0; j < 9; ++j) { uint2 u = tp[j]; pkt[2*j] = u.x; pkt[2*j+1] = u.y; }
    }

    if (tid < F_) tok[tid] = feats[b * F_ + tid];
    __syncthreads();
    for (int idx = tid; idx < F_ * K_; idx += 512) {
        int f = idx >> 4, k = idx & 15;
        emb2[f * ESTR + k] = hbits(v[(size_t)tok[f] * K_ + k]);
    }
    __syncthreads();

    // P0: all 741 pair products -> Y2 (f16), level2 -> global (coalesced 2B)
#pragma unroll
    for (int pp = 0; pp < 2; ++pp) {
        int p = pp * 512 + tid;
        if (p < P_) {
            unsigned pk = pp == 0 ? pk_p0 : pk_p1;
            int o1 = (int)(pk & 2047u);
            int o2 = (int)((pk >> 11) & 2047u);
            uint4 ua0 = *(const uint4*)&emb2[o1];
            uint4 ua1 = *(const uint4*)&emb2[o1 + 8];
            uint4 uc0 = *(const uint4*)&emb2[o2];
            uint4 uc1 = *(const uint4*)&emb2[o2 + 8];
            float s = 0.f;
            uint4 y0, y1;
#define PKMUL(dst, a, c) {                                                    \
            half2v _a = __builtin_bit_cast(half2v, a);                        \
            half2v _c = __builtin_bit_cast(half2v, c);                        \
            half2v _y = _a * _c;                                              \
            dst = __builtin_bit_cast(unsigned, _y);                           \
            s = hdot2(a, c, s); }
            PKMUL(y0.x, ua0.x, uc0.x); PKMUL(y0.y, ua0.y, uc0.y);
            PKMUL(y0.z, ua0.z, uc0.z); PKMUL(y0.w, ua0.w, uc0.w);
            PKMUL(y1.x, ua1.x, uc1.x); PKMUL(y1.y, ua1.y, uc1.y);
            PKMUL(y1.z, ua1.z, uc1.z); PKMUL(y1.w, ua1.w, uc1.w);
#undef PKMUL
            *(uint4*)&Y2[p * YSTR] = y0;
            *(uint4*)&Y2[p * YSTR + 8] = y1;
            lrow[p] = hbits(s);
        }
    }
    __syncthreads();

    // P1: 18 consecutive triples per thread; Y row cached in registers across runs
    unsigned cur = 0xFFFFFFFFu;
    uint4 uy0, uy1;
    unsigned resp[9];
#pragma unroll
    for (int j = 0; j < 18; ++j) {
        int t = t0 + j;
        unsigned short r = 0;
        if (t < T_) {
            unsigned pk = pkt[j];
            unsigned yb = pk & 32767u;
            int o3 = (int)(pk >> 15);
            if (yb != cur) {
                cur = yb;
                uy0 = *(const uint4*)&Y2[yb];
                uy1 = *(const uint4*)&Y2[yb + 8];
            }
            uint4 ue0 = *(const uint4*)&emb2[o3];
            uint4 ue1 = *(const uint4*)&emb2[o3 + 8];
            float s = 0.f;
            s = hdot2(uy0.x, ue0.x, s); s = hdot2(uy0.y, ue0.y, s);
            s = hdot2(uy0.z, ue0.z, s); s = hdot2(uy0.w, ue0.w, s);
            s = hdot2(uy1.x, ue1.x, s); s = hdot2(uy1.y, ue1.y, s);
            s = hdot2(uy1.z, ue1.z, s); s = hdot2(uy1.w, ue1.w, s);
            r = hbits(s);
        }
        if (j & 1) resp[j >> 1] |= ((unsigned)r) << 16;
        else       resp[j >> 1] = (unsigned)r;
    }
    __syncthreads();   // all Y2 reads complete -> safe to overlay

    // stage packed results into LDS (overlay), byte offset 36*tid (4B-aligned)
#pragma unroll
    for (int j = 0; j < 9; ++j)
        bufw[9 * tid + j] = resp[j];
    if (tid < 3) lrow[P_ + tid] = 0;   // pad cols 741..743
    __syncthreads();

    // coalesced flush: buf f16 [0..9176) -> lrow[TBASE..LS2) ; 9176/8 = 1147 uint4
    uint4* dst = (uint4*)(lrow + TBASE);
    const uint4* src = (const uint4*)bufw;
    for (int idx = tid; idx < 1147; idx += 512)
        dst[idx] = src[idx];
}

// ---------- kernel 2: column partial stats, uint4 loads, 8 cols/thread --------------
__global__ __launch_bounds__(256) void stats2_k(const unsigned short* __restrict__ levels,
                                                float* __restrict__ psum,
                                                float* __restrict__ psumsq) {
    int g = blockIdx.x * 256 + threadIdx.x;
    if (g >= NG) return;
    int sy = blockIdx.y;
    const uint4* p = (const uint4*)levels + (size_t)(sy * (B_ / NSPLIT)) * NG + g;
    float s1[8] = {0,0,0,0,0,0,0,0};
    float s2[8] = {0,0,0,0,0,0,0,0};
#pragma unroll 4
    for (int r = 0; r < B_ / NSPLIT; ++r) {
        uint4 u = p[(size_t)r * NG];
        unsigned uu[4] = {u.x, u.y, u.z, u.w};
#pragma unroll
        for (int q = 0; q < 4; ++q) {
            float x0 = __uint_as_float((uu[q] & 0xffffu) ? 0 : 0);  // placeholder avoid
            (void)x0;
            float a = f16f((unsigned short)(uu[q] & 0xffffu));
            float c = f16f((unsigned short)(uu[q] >> 16));
            s1[2*q]   += a; s2[2*q]   += a * a;
            s1[2*q+1] += c; s2[2*q+1] += c * c;
        }
    }
    float* d1 = psum   + (size_t)sy * LS2 + g * 8;
    float* d2 = psumsq + (size_t)sy * LS2 + g * 8;
#pragma unroll
    for (int k = 0; k < 8; ++k) { d1[k] = s1[k]; d2[k] = s2[k]; }
}

// ---------- kernel 3: BN finalize -> per-column f16 scale + scalar C ----------------
__global__ __launch_bounds__(256) void finalize_k(const float* __restrict__ psum,
                                                  const float* __restrict__ psumsq,
                                                  const float* __restrict__ gamma2,
                                                  const float* __restrict__ beta2,
                                                  const float* __restrict__ gw2,
                                                  const float* __restrict__ gamma3,
                                                  const float* __restrict__ beta3,
                                                  const float* __restrict__ gw3,
                                                  unsigned short* __restrict__ scale_h,
                                                  float* __restrict__ Cacc) {
    int col = blockIdx.x * 256 + threadIdx.x;
    float c = 0.f;
    if (col < LS2) {
        float s1 = 0.f, s2 = 0.f;
#pragma unroll 8
        for (int sy = 0; sy < NSPLIT; ++sy) {
            s1 += psum[(size_t)sy * LS2 + col];
            s2 += psumsq[(size_t)sy * LS2 + col];
        }
        float g = 0.f, be = 0.f, gw = 0.f;
        if (col < P_) {
            g = gamma2[col]; be = beta2[col]; gw = gw2[col];
        } else if (col >= TBASE && col < TBASE + T_) {
            int t = col - TBASE;
            g = gamma3[t]; be = beta3[t]; gw = gw3[t];
        }
        float mean = s1 * (1.0f / B_);
        float var  = s2 * (1.0f / B_) - mean * mean;
        float inv  = 1.0f / sqrtf(var + EPS_);
        scale_h[col] = hbits(gw * g * inv);
        c = gw * (be - g * inv * mean);      // gw==0 on pad cols -> 0
    }
    __shared__ float red[256];
    red[threadIdx.x] = c;
    __syncthreads();
    for (int s = 128; s > 0; s >>= 1) {
        if (threadIdx.x < s) red[threadIdx.x] += red[threadIdx.x + s];
        __syncthreads();
    }
    if (threadIdx.x == 0) atomicAdd(Cacc, red[0]);
}

// ---------- kernel 4: weighted row sum (fdot2) + linear term -> logits --------------
__global__ __launch_bounds__(256) void out_k(const unsigned short* __restrict__ levels,
                                             const unsigned short* __restrict__ scale_h,
                                             const int* __restrict__ feats,
                                             const float* __restrict__ w,
                                             const float* __restrict__ Cacc,
                                             const float* __restrict__ bias,
                                             float* __restrict__ out) {
    int b = blockIdx.x, tid = threadIdx.x;
    const uint4* lv = (const uint4*)(levels + (size_t)b * LS2);
    const uint4* sv = (const uint4*)scale_h;
    float acc = 0.f;
    for (int idx = tid; idx < NG; idx += 256) {
        uint4 u = lv[idx];
        uint4 s = sv[idx];
        acc = hdot2(u.x, s.x, acc);
        acc = hdot2(u.y, s.y, acc);
        acc = hdot2(u.z, s.z, acc);
        acc = hdot2(u.w, s.w, acc);
    }
    if (tid < F_) acc += w[feats[b * F_ + tid]];   // linear term
    __shared__ float red[256];
    red[tid] = acc;
    __syncthreads();
    for (int s = 128; s > 0; s >>= 1) {
        if (tid < s) red[tid] += red[tid + s];
        __syncthreads();
    }
    if (tid == 0) out[b] = red[0] + Cacc[0] + bias[0];
}

// ---------- host launcher -----------------------------------------------------------
extern "C" void kernel_launch(void* const* d_in, const int* in_sizes, int n_in,
                              void* d_out, int out_size, void* d_ws, size_t ws_size,
                              hipStream_t stream) {
    const int*   feats  = (const int*)d_in[0];
    const float* w      = (const float*)d_in[1];
    const float* v      = (const float*)d_in[2];
    const float* bias   = (const float*)d_in[3];
    const float* gamma2 = (const float*)d_in[4];
    const float* beta2  = (const float*)d_in[5];
    const float* gw2    = (const float*)d_in[6];
    const float* gamma3 = (const float*)d_in[7];
    const float* beta3  = (const float*)d_in[8];
    const float* gw3    = (const float*)d_in[9];
    const int*   rows   = (const int*)d_in[10];
    const int*   cols   = (const int*)d_in[11];
    const int*   i1     = (const int*)d_in[12];
    const int*   i2     = (const int*)d_in[13];
    const int*   i3     = (const int*)d_in[14];
    float*       out    = (float*)d_out;
    float*       ws     = (float*)d_ws;

    // workspace layout (float offsets)
    float*          psum    = ws;                               // 32*9920 = 317440
    float*          psumsq  = ws + 317440;                      // 317440
    float*          Cacc    = ws + 634880;                      // 1
    unsigned short* scale_h = (unsigned short*)(ws + 634944);   // 9984 u16 = 4992 f
    unsigned*       pidx    = (unsigned*)(ws + 639936);         // ~9960 u32
    unsigned short* levels  = (unsigned short*)(ws + 649984);   // 1024*9920 f16, 16B-al

    prep_k<<<(NC_ + 255) / 256, 256, 0, stream>>>(rows, cols, i1, i2, i3, pidx, Cacc);
    levels_k<<<B_, 512, 0, stream>>>(feats, v, pidx, levels);
    stats2_k<<<dim3((NG + 255) / 256, NSPLIT), 256, 0, stream>>>(levels, psum, psumsq);
    finalize_k<<<(LS2 + 255) / 256, 256, 0, stream>>>(psum, psumsq,
                                                      gamma2, beta2, gw2,
                                                      gamma3, beta3, gw3, scale_h, Cacc);
    out_k<<<B_, 256, 0, stream>>>(levels, scale_h, feats, w, Cacc, bias, out);
}